// Round 22
// baseline (81.578 us; speedup 1.0000x reference)
//
#include <hip/hip_runtime.h>
#include <hip/hip_bf16.h>

#define SEQ  256
#define DIM  20
#define NCLS 5
#define ALPHA 2.8853900817779268f   // 2*log2(e), folded into recurrent weights

typedef short  bf16x8 __attribute__((ext_vector_type(8)));
typedef float  f32x4  __attribute__((ext_vector_type(4)));
typedef float  v2f    __attribute__((ext_vector_type(2)));

// tanh from PRE-SCALED input (xs = 2*log2e*pre): 1 - 2/(exp2(xs)+1).
// One v_rcp serves both lanes (paired reciprocal; d>=1 so no overflow).
__device__ __forceinline__ v2f fast_tanh2_s(v2f xs) {
    v2f e;
    e.x = __builtin_amdgcn_exp2f(xs.x);
    e.y = __builtin_amdgcn_exp2f(xs.y);
    v2f d = e + 1.0f;
    const float r = __builtin_amdgcn_rcpf(d.x * d.y);
    v2f inv;
    inv.x = d.y * r;
    inv.y = d.x * r;
    return __builtin_elementwise_fma((v2f)(-2.0f), inv, (v2f)(1.0f));
}

__device__ __forceinline__ int cvt_pk_bf16(float lo, float hi) {
    int r;
    asm("v_cvt_pk_bf16_f32 %0, %1, %2" : "=v"(r) : "v"(lo), "v"(hi));
    return r;
}

// v_permlane32_swap_b32 (S1 semantics, established r8/r9):
//   a' = {a_low, b_low}; b' = {a_high, b_high}
__device__ __forceinline__ void pl32swap(int &a, int &b) {
    asm("v_permlane32_swap_b32 %0, %1" : "+v"(a), "+v"(b));
}

// Recurrent k-permutation (A-column kappa holds unit perm(kappa)):
// [0-3]->u0-3, [4-7]->u8-11, [8-11]->u4-7, [12-15]->u12-15, [16-19]->u16-19.
__device__ __forceinline__ int permk(int k) {
    return (k >= 4 && k < 8) ? k + 4 : (k >= 8 && k < 12) ? k - 4 : k;
}

union I4B { int i[4]; bf16x8 f; };

// ============================================================================
// Producer/consumer wave specialization. Block = 512 thr = 8 waves:
//   waves 0-3 (H): tanh -> pack -> swap -> h-MFMA for tile (wid&3)
//   waves 4-7 (E): token+gather pipeline, Be cvt, e-MFMA; one-way handoff of
//                  aePre via 2-deep LDS ring, ONE __syncthreads per step.
// Schedule (verified): E@iter s writes ring[(s+1)&1]; H@iter s reads ring[s&1]
//   -> disjoint every interval; E's overwrite of a slot is 2 barriers after
//   the read of that slot; __syncthreads drains LDS ops on both sides.
// Barrier counts: both roles execute 2 prologue syncs + 254 loop syncs.
// 2 waves/SIMD: H-wave dependency bubbles are filled by E-wave issue.
// ============================================================================
__global__ __launch_bounds__(512)
__attribute__((amdgpu_waves_per_eu(2, 2)))
void rnn_pc(const int* __restrict__ x,
            const float* __restrict__ emb,
            const float* __restrict__ W_ih,
            const float* __restrict__ W_hh,
            const float* __restrict__ W_cls,
            const float* __restrict__ b_cls,
            float* __restrict__ out, int B)
{
    __shared__ f32x4 ring[4][2][2][64];   // [tile][buf][ae0/ae1][lane] = 16 KB

    const int tid  = (int)threadIdx.x;
    const int wid  = tid >> 6;            // 0..7
    const int lane = tid & 63;
    const int t    = wid & 3;             // tile slot in block
    const bool isE = (wid >= 4);          // producer role
    const int row0 = ((int)blockIdx.x * 4 + t) * 16;
    const int c = lane & 15;              // batch column
    const int q = lane >> 4;              // quadrant

    // A fragments: lane holds A[row=c][k=8q+j], zero outside bounds.
    auto loadA = [&](const float* M, int U0, int ROWS, bool pk, float scale) {
        bf16x8 f;
        const int uu = U0 + c;
        const int ur = uu < ROWS ? uu : 0;
#pragma unroll
        for (int j = 0; j < 8; ++j) {
            const int kk = 8 * q + j;
            const int kp = pk ? permk(kk) : kk;
            const int kr = kp < DIM ? kp : 0;
            float v = M[ur * DIM + kr] * scale;
            v = (uu < ROWS && kk < DIM) ? v : 0.0f;
            __hip_bfloat16 hb = __float2bfloat16(v);
            f[j] = *reinterpret_cast<short*>(&hb);
        }
        return f;
    };
    const f32x4 zf = {0.0f, 0.0f, 0.0f, 0.0f};

    if (isE) {
        // ==================== PRODUCER ====================
        const bf16x8 A0e = loadA(W_ih,  0, DIM, false, ALPHA);  // units 0-15
        const bf16x8 A1e = loadA(W_ih, 16, DIM, false, ALPHA);  // units 16-19
        const int eoff0 = (q == 0) ? 0 : (q == 1) ? 8 : 16;
        const int eoff1 = (q == 0) ? 4 : (q == 1) ? 12 : 16;
        const int* xp = x + (size_t)(row0 + c) * SEQ;

        auto conv = [&](int tok) {
            const f32x4 lo = *(const f32x4*)(emb + (size_t)tok * DIM + eoff0);
            const f32x4 hi = *(const f32x4*)(emb + (size_t)tok * DIM + eoff1);
            const bool nz = (tok != 0);          // padding_idx = 0
            I4B Be;
            Be.i[0] = nz ? cvt_pk_bf16(lo[0], lo[1]) : 0;
            Be.i[1] = nz ? cvt_pk_bf16(lo[2], lo[3]) : 0;
            Be.i[2] = nz ? cvt_pk_bf16(hi[0], hi[1]) : 0;
            Be.i[3] = nz ? cvt_pk_bf16(hi[2], hi[3]) : 0;
            return Be;
        };

        // prologue: ae(0) -> ring[0], ae(1) -> ring[1]
        {
            I4B Be0 = conv(xp[0]);
            ring[t][0][0][lane] = __builtin_amdgcn_mfma_f32_16x16x32_bf16(A0e, Be0.f, zf, 0, 0, 0);
            ring[t][0][1][lane] = __builtin_amdgcn_mfma_f32_16x16x32_bf16(A1e, Be0.f, zf, 0, 0, 0);
            I4B Be1 = conv(xp[1]);
            ring[t][1][0][lane] = __builtin_amdgcn_mfma_f32_16x16x32_bf16(A0e, Be1.f, zf, 0, 0, 0);
            ring[t][1][1][lane] = __builtin_amdgcn_mfma_f32_16x16x32_bf16(A1e, Be1.f, zf, 0, 0, 0);
        }
        // stages A..D = e(2)..e(5); tokens x[6..9] in flight
        const int tk2 = xp[2], tk3 = xp[3], tk4 = xp[4], tk5 = xp[5];
        f32x4 loA, hiA, loB, hiB, loC, hiC, loD, hiD;
        bool nzA, nzB, nzC, nzD;
        loA = *(const f32x4*)(emb + (size_t)tk2 * DIM + eoff0);
        hiA = *(const f32x4*)(emb + (size_t)tk2 * DIM + eoff1);
        nzA = (tk2 != 0);
        loB = *(const f32x4*)(emb + (size_t)tk3 * DIM + eoff0);
        hiB = *(const f32x4*)(emb + (size_t)tk3 * DIM + eoff1);
        nzB = (tk3 != 0);
        loC = *(const f32x4*)(emb + (size_t)tk4 * DIM + eoff0);
        hiC = *(const f32x4*)(emb + (size_t)tk4 * DIM + eoff1);
        nzC = (tk4 != 0);
        loD = *(const f32x4*)(emb + (size_t)tk5 * DIM + eoff0);
        hiD = *(const f32x4*)(emb + (size_t)tk5 * DIM + eoff1);
        nzD = (tk5 != 0);
        int tokG0 = xp[6], tokG1 = xp[7], tokG2 = xp[8], tokG3 = xp[9];

        __syncthreads();   // sync1: ring[0], ring[1] visible
        __syncthreads();   // sync2: H consumed ring[0]

        // E iter s: stage A = e(s+1); produce ae(s+1) -> ring[(s+1)&1];
        // gather e(s+5) via tokG0 = x[s+5]; load token x[min(s+9,255)]
#define EBODY(TIDX, PAR)                                                       \
        {                                                                      \
            const f32x4 loN = *(const f32x4*)(emb + (size_t)tokG0 * DIM + eoff0); \
            const f32x4 hiN = *(const f32x4*)(emb + (size_t)tokG0 * DIM + eoff1); \
            const bool  nzN = (tokG0 != 0);                                    \
            const int tokNew = xp[(TIDX)];                                     \
            I4B Be;                                                            \
            Be.i[0] = nzA ? cvt_pk_bf16(loA[0], loA[1]) : 0;                   \
            Be.i[1] = nzA ? cvt_pk_bf16(loA[2], loA[3]) : 0;                   \
            Be.i[2] = nzA ? cvt_pk_bf16(hiA[0], hiA[1]) : 0;                   \
            Be.i[3] = nzA ? cvt_pk_bf16(hiA[2], hiA[3]) : 0;                   \
            ring[t][(PAR)][0][lane] = __builtin_amdgcn_mfma_f32_16x16x32_bf16(A0e, Be.f, zf, 0, 0, 0); \
            ring[t][(PAR)][1][lane] = __builtin_amdgcn_mfma_f32_16x16x32_bf16(A1e, Be.f, zf, 0, 0, 0); \
            loA = loB; hiA = hiB; nzA = nzB;                                   \
            loB = loC; hiB = hiC; nzB = nzC;                                   \
            loC = loD; hiC = hiD; nzC = nzD;                                   \
            loD = loN; hiD = hiN; nzD = nzN;                                   \
            tokG0 = tokG1; tokG1 = tokG2; tokG2 = tokG3; tokG3 = tokNew;       \
        }

#pragma unroll 4
        for (int s = 1; s <= 240; ++s) {
            EBODY(s + 9, (s + 1) & 1)
            __syncthreads();
        }
#pragma unroll 2
        for (int s = 241; s <= 254; ++s) {
            EBODY((s + 9 < SEQ) ? (s + 9) : (SEQ - 1), (s + 1) & 1)
            __syncthreads();
        }
        // producer done (254 + 2 syncs, matching consumer)
    } else {
        // ==================== CONSUMER ====================
        const bf16x8 A0h = loadA(W_hh,  0, DIM,  true, ALPHA);  // units 0-15
        const bf16x8 A1h = loadA(W_hh, 16, DIM,  true, ALPHA);  // units 16-19
        const bf16x8 Acl = loadA(W_cls, 0, NCLS, true, 1.0f);   // classes 0-4
        float bias[4];
#pragma unroll
        for (int j = 0; j < 4; ++j) {
            const int idx = 4 * q + j;
            bias[j] = (idx < NCLS) ? b_cls[idx] : 0.0f;
        }

        __syncthreads();   // sync1: ring[0], ring[1] written by producer
        f32x4 acc0 = ring[t][0][0][lane];   // acc(0) = ae(0)  (Bh(0) = 0)
        f32x4 acc1 = ring[t][0][1][lane];
        __syncthreads();   // sync2: safe for producer to overwrite ring[0]

        I4B Bh;

        // H iter s: Bh(s) = pack(tanh(acc(s-1))); acc(s) = h-MFMA + ae(s)
#define HBODY(S)                                                               \
        {                                                                      \
            const f32x4 r0 = ring[t][(S) & 1][0][lane];  /* issue early */     \
            const f32x4 r1 = ring[t][(S) & 1][1][lane];                        \
            const v2f p2 = fast_tanh2_s((v2f){acc1[0], acc1[1]});              \
            const v2f p3 = fast_tanh2_s((v2f){acc1[2], acc1[3]});              \
            int tp0 = cvt_pk_bf16(p2.x, p2.y);                                 \
            int tp1 = cvt_pk_bf16(p3.x, p3.y);                                 \
            const v2f p0 = fast_tanh2_s((v2f){acc0[0], acc0[1]});              \
            const v2f p1 = fast_tanh2_s((v2f){acc0[2], acc0[3]});              \
            int w0 = cvt_pk_bf16(p0.x, p0.y);                                  \
            int w1 = cvt_pk_bf16(p1.x, p1.y);                                  \
            pl32swap(w0, tp0);   /* w'={w_lo,t_lo}; t'={w_hi,t_hi} */          \
            pl32swap(w1, tp1);                                                 \
            Bh.i[0] = w0; Bh.i[1] = w1; Bh.i[2] = tp0; Bh.i[3] = tp1;          \
            acc1 = __builtin_amdgcn_mfma_f32_16x16x32_bf16(A1h, Bh.f, r1, 0, 0, 0); \
            acc0 = __builtin_amdgcn_mfma_f32_16x16x32_bf16(A0h, Bh.f, r0, 0, 0, 0); \
        }

#pragma unroll 2
        for (int s = 1; s <= 240; ++s) {
            HBODY(s)
            __syncthreads();
        }
#pragma unroll 2
        for (int s = 241; s <= 254; ++s) {
            HBODY(s)
            __syncthreads();
        }
        // final step 255 (ring[1] = ae(255), written before last barrier)
        HBODY(255)

        // h(256) = tanh(acc(255)) -> Bh; classifier
        {
            const v2f p2 = fast_tanh2_s((v2f){acc1[0], acc1[1]});
            const v2f p3 = fast_tanh2_s((v2f){acc1[2], acc1[3]});
            int tp0 = cvt_pk_bf16(p2.x, p2.y);
            int tp1 = cvt_pk_bf16(p3.x, p3.y);
            const v2f p0 = fast_tanh2_s((v2f){acc0[0], acc0[1]});
            const v2f p1 = fast_tanh2_s((v2f){acc0[2], acc0[3]});
            int w0 = cvt_pk_bf16(p0.x, p0.y);
            int w1 = cvt_pk_bf16(p1.x, p1.y);
            pl32swap(w0, tp0);
            pl32swap(w1, tp1);
            Bh.i[0] = w0; Bh.i[1] = w1; Bh.i[2] = tp0; Bh.i[3] = tp1;
        }
        const f32x4 y = __builtin_amdgcn_mfma_f32_16x16x32_bf16(Acl, Bh.f, zf, 0, 0, 0);
        if (row0 < B) {
            float* orow = out + (size_t)(row0 + c) * NCLS;
            if (q == 0) {          // rows 0-3 = classes 0-3
                orow[0] = y[0] + bias[0];
                orow[1] = y[1] + bias[1];
                orow[2] = y[2] + bias[2];
                orow[3] = y[3] + bias[3];
            } else if (q == 1) {   // row 4 = class 4
                orow[4] = y[0] + bias[0];
            }
        }
    }
}

extern "C" void kernel_launch(void* const* d_in, const int* in_sizes, int n_in,
                              void* d_out, int out_size, void* d_ws, size_t ws_size,
                              hipStream_t stream) {
    const int*   x     = (const int*)d_in[0];
    const float* emb   = (const float*)d_in[1];
    const float* W_ih  = (const float*)d_in[2];
    const float* W_hh  = (const float*)d_in[3];
    const float* W_cls = (const float*)d_in[4];
    const float* b_cls = (const float*)d_in[5];
    float* out = (float*)d_out;

    const int B = in_sizes[0] / SEQ;            // 16384
    const int tiles = (B + 15) / 16;             // 1024
    const int grid = (tiles + 3) / 4;            // 256 blocks x 512 threads
    rnn_pc<<<grid, 512, 0, stream>>>(x, emb, W_ih, W_hh, W_cls, b_cls, out, B);
}